// Round 1
// baseline (435.688 us; speedup 1.0000x reference)
//
#include <hip/hip_runtime.h>
#include <math.h>

// Problem constants (match reference)
#define NROWS 65536          // B*S = 16*4096
#define CIN   768
#define DDIM  8
#define LLEV  8
#define QCOUNT 524288.0      // NROWS * DDIM

// One wave (64 lanes) processes 2 rows. Block = 4 waves = 8 rows.
// Lane mapping: dg = lane&7 (quantizer dim), lev = lane>>3 (codebook level).

__global__ __launch_bounds__(256) void fsq_main(
    const float* __restrict__ z, const float* __restrict__ u,
    const float* __restrict__ Wc, const float* __restrict__ bc,
    const float* __restrict__ We, const float* __restrict__ be,
    const float* __restrict__ cb, float* __restrict__ zq,
    double* __restrict__ qacc)
{
    const int lane = threadIdx.x & 63;
    const int wid  = threadIdx.x >> 6;
    const int gw   = blockIdx.x * 4 + wid;      // global wave id, 0..32767
    const int row0 = gw * 2;
    const int row1 = row0 + 1;
    const int dg   = lane & 7;
    const int lev  = lane >> 3;

    // per-lane constants
    const float  cb_mine = cb[dg * LLEV + lev];
    const double bc_mine = (double)bc[dg];

    const float4* __restrict__ z4  = (const float4*)z;
    const float4* __restrict__ Wc4 = (const float4*)Wc;

    // ---------------- compress: zc = z @ Wc (+bc) ----------------
    // Each lane: 12 contiguous-by-wave z elements (3 float4), partials for all 8 d.
    // f32 FMA within a 4-element chunk, f64 chunk accumulation (decision path
    // needs ~1e-8 accuracy to avoid argmax tie flips vs the f64 np reference).
    double da0[8], da1[8];
#pragma unroll
    for (int d = 0; d < 8; ++d) { da0[d] = 0.0; da1[d] = 0.0; }

#pragma unroll
    for (int j = 0; j < 3; ++j) {
        const int fi = lane + 64 * j;                    // float4 index in row
        const float4 zv0 = z4[(size_t)row0 * 192 + fi];
        const float4 zv1 = z4[(size_t)row1 * 192 + fi];
        float f0[8], f1[8];
#pragma unroll
        for (int d = 0; d < 8; ++d) { f0[d] = 0.f; f1[d] = 0.f; }

#define COMP_STEP(comp, koff)                                              \
        {                                                                  \
            const int c = fi * 4 + (koff);                                 \
            const float4 wA = Wc4[c * 2];                                  \
            const float4 wB = Wc4[c * 2 + 1];                              \
            const float a0 = zv0.comp, a1 = zv1.comp;                      \
            f0[0] = fmaf(a0, wA.x, f0[0]); f0[1] = fmaf(a0, wA.y, f0[1]);  \
            f0[2] = fmaf(a0, wA.z, f0[2]); f0[3] = fmaf(a0, wA.w, f0[3]);  \
            f0[4] = fmaf(a0, wB.x, f0[4]); f0[5] = fmaf(a0, wB.y, f0[5]);  \
            f0[6] = fmaf(a0, wB.z, f0[6]); f0[7] = fmaf(a0, wB.w, f0[7]);  \
            f1[0] = fmaf(a1, wA.x, f1[0]); f1[1] = fmaf(a1, wA.y, f1[1]);  \
            f1[2] = fmaf(a1, wA.z, f1[2]); f1[3] = fmaf(a1, wA.w, f1[3]);  \
            f1[4] = fmaf(a1, wB.x, f1[4]); f1[5] = fmaf(a1, wB.y, f1[5]);  \
            f1[6] = fmaf(a1, wB.z, f1[6]); f1[7] = fmaf(a1, wB.w, f1[7]);  \
        }
        COMP_STEP(x, 0)
        COMP_STEP(y, 1)
        COMP_STEP(z, 2)
        COMP_STEP(w, 3)
#undef COMP_STEP

#pragma unroll
        for (int d = 0; d < 8; ++d) {
            da0[d] += (double)f0[d];
            da1[d] += (double)f1[d];
        }
    }

    // Distributing butterfly: reduce 8 per-lane partial arrays across 64 lanes,
    // delivering zc[d] to lanes with (lane&7)==d. f64, fixed order, no dynamic
    // register indexing (static selects only).
    const int b0 = lane & 1, b1 = (lane >> 1) & 1, b2 = (lane >> 2) & 1;
#define REDUCE_TO_MINE(da, out)                                            \
    {                                                                      \
        double k0 = b0 ? da[1] : da[0], s0 = b0 ? da[0] : da[1];           \
        double k1 = b0 ? da[3] : da[2], s1 = b0 ? da[2] : da[3];           \
        double k2 = b0 ? da[5] : da[4], s2 = b0 ? da[4] : da[5];           \
        double k3 = b0 ? da[7] : da[6], s3 = b0 ? da[6] : da[7];           \
        k0 += __shfl_xor(s0, 1); k1 += __shfl_xor(s1, 1);                  \
        k2 += __shfl_xor(s2, 1); k3 += __shfl_xor(s3, 1);                  \
        double m0 = b1 ? k1 : k0, t0 = b1 ? k0 : k1;                       \
        double m1 = b1 ? k3 : k2, t1 = b1 ? k2 : k3;                       \
        m0 += __shfl_xor(t0, 2); m1 += __shfl_xor(t1, 2);                  \
        double r = b2 ? m1 : m0, tq = b2 ? m0 : m1;                        \
        r += __shfl_xor(tq, 4);                                            \
        r += __shfl_xor(r, 8);                                             \
        r += __shfl_xor(r, 16);                                            \
        r += __shfl_xor(r, 32);                                            \
        out = r;                                                           \
    }
    double zc0, zc1;
    REDUCE_TO_MINE(da0, zc0)
    REDUCE_TO_MINE(da1, zc1)
#undef REDUCE_TO_MINE
    zc0 += bc_mine;
    zc1 += bc_mine;

    // ---------------- gumbel + argmax (per (row, dg)) ----------------
    // u[row][dg][lev] -> permuted-coalesced 256B read per row per wave
    const double uv0 = (double)u[(size_t)row0 * 64 + dg * 8 + lev] + 1e-10;
    const double uv1 = (double)u[(size_t)row1 * 64 + dg * 8 + lev] + 1e-10;
    const double g0 = -log(-log(uv0));
    const double g1 = -log(-log(uv1));
    double n0 = g0 - fabs(zc0 - (double)cb_mine);   // TAU = 1
    double n1 = g1 - fabs(zc1 - (double)cb_mine);

    int   l0 = lev, l1 = lev;
    float c0 = cb_mine, c1 = cb_mine;
#pragma unroll
    for (int s = 8; s <= 32; s <<= 1) {             // reduce over lev bits (3,4,5)
        const double on0 = __shfl_xor(n0, s);
        const int    ol0 = __shfl_xor(l0, s);
        const float  oc0 = __shfl_xor(c0, s);
        const bool   t0  = (on0 > n0) || (on0 == n0 && ol0 < l0);  // first-max tie-break
        n0 = t0 ? on0 : n0; l0 = t0 ? ol0 : l0; c0 = t0 ? oc0 : c0;
        const double on1 = __shfl_xor(n1, s);
        const int    ol1 = __shfl_xor(l1, s);
        const float  oc1 = __shfl_xor(c1, s);
        const bool   t1  = (on1 > n1) || (on1 == n1 && ol1 < l1);
        n1 = t1 ? on1 : n1; l1 = t1 ? ol1 : l1; c1 = t1 ? oc1 : c1;
    }
    // c0/c1: selected codebook value for dim dg (valid in every lane)

    // ---------------- quantization error partial ----------------
    const double e0 = zc0 - (double)c0;
    const double e1 = zc1 - (double)c1;
    double q = e0 * e0 + e1 * e1;
    q += __shfl_xor(q, 1);
    q += __shfl_xor(q, 2);
    q += __shfl_xor(q, 4);      // lane 0 now holds sum over d = 0..7 (both rows)
    if (lane == 0) atomicAdd(qacc, q);

    // broadcast all 8 codes to every lane
    float code0[8], code1[8];
#pragma unroll
    for (int d = 0; d < 8; ++d) {
        code0[d] = __shfl(c0, (lane & 56) | d);
        code1[d] = __shfl(c1, (lane & 56) | d);
    }

    // ---------------- expand: z_q = codes @ We + be ----------------
    const float4* __restrict__ We4 = (const float4*)We;
    const float4* __restrict__ be4 = (const float4*)be;
    float4* __restrict__ zq4 = (float4*)zq;
#pragma unroll
    for (int j = 0; j < 3; ++j) {
        const int fi = lane + 64 * j;
        const float4 bv = be4[fi];
        float4 o0 = bv, o1 = bv;
#pragma unroll
        for (int d = 0; d < 8; ++d) {
            const float4 wv = We4[d * 192 + fi];
            o0.x = fmaf(code0[d], wv.x, o0.x);
            o0.y = fmaf(code0[d], wv.y, o0.y);
            o0.z = fmaf(code0[d], wv.z, o0.z);
            o0.w = fmaf(code0[d], wv.w, o0.w);
            o1.x = fmaf(code1[d], wv.x, o1.x);
            o1.y = fmaf(code1[d], wv.y, o1.y);
            o1.z = fmaf(code1[d], wv.z, o1.z);
            o1.w = fmaf(code1[d], wv.w, o1.w);
        }
        zq4[(size_t)row0 * 192 + fi] = o0;
        zq4[(size_t)row1 * 192 + fi] = o1;
    }
}

__global__ void fsq_tail(const double* __restrict__ qacc, float* __restrict__ out)
{
    out[0] = (float)(qacc[0] * (1.0 / QCOUNT));
}

extern "C" void kernel_launch(void* const* d_in, const int* in_sizes, int n_in,
                              void* d_out, int out_size, void* d_ws, size_t ws_size,
                              hipStream_t stream)
{
    const float* z  = (const float*)d_in[0];
    const float* u  = (const float*)d_in[1];
    const float* Wc = (const float*)d_in[2];
    const float* bc = (const float*)d_in[3];
    const float* We = (const float*)d_in[4];
    const float* be = (const float*)d_in[5];
    const float* cb = (const float*)d_in[6];
    // d_in[7] = codebook_mask: all levels == 8 -> mask all true, unused.

    float*  zq   = (float*)d_out;
    double* qacc = (double*)d_ws;

    hipMemsetAsync(d_ws, 0, sizeof(double), stream);

    // 8192 blocks x 256 threads: 32768 waves x 2 rows = 65536 rows, exact.
    fsq_main<<<dim3(NROWS / 8), dim3(256), 0, stream>>>(z, u, Wc, bc, We, be, cb, zq, qacc);
    fsq_tail<<<dim3(1), dim3(1), 0, stream>>>(qacc, zq + (size_t)NROWS * CIN);
}

// Round 2
// 211.864 us; speedup vs baseline: 2.0565x; 2.0565x over previous
//
#include <hip/hip_runtime.h>
#include <math.h>

// Problem constants (match reference)
#define NROWS 65536          // B*S = 16*4096
#define CIN   768
#define DDIM  8
#define LLEV  8
#define QCOUNT 524288.0      // NROWS * DDIM
#define NBLOCKS (NROWS / 8)  // 8192: 4 waves/block, 2 rows/wave

// One wave (64 lanes) processes 2 rows. Block = 4 waves = 8 rows.
// Lane mapping: dg = lane&7 (quantizer dim), lev = lane>>3 (codebook level).
// USE_BPART: 1 -> per-block partial store to bpart[] (no contended atomics)
//            0 -> legacy single-address atomicAdd fallback (small ws_size)

template <int USE_BPART>
__global__ __launch_bounds__(256) void fsq_main(
    const float* __restrict__ z, const float* __restrict__ u,
    const float* __restrict__ Wc, const float* __restrict__ bc,
    const float* __restrict__ We, const float* __restrict__ be,
    const float* __restrict__ cb, float* __restrict__ zq,
    double* __restrict__ bpart)
{
    __shared__ double wsum[4];

    const int lane = threadIdx.x & 63;
    const int wid  = threadIdx.x >> 6;
    const int gw   = blockIdx.x * 4 + wid;      // global wave id, 0..32767
    const int row0 = gw * 2;
    const int row1 = row0 + 1;
    const int dg   = lane & 7;
    const int lev  = lane >> 3;

    // per-lane constants
    const float  cb_mine = cb[dg * LLEV + lev];
    const double bc_mine = (double)bc[dg];

    const float4* __restrict__ z4  = (const float4*)z;
    const float4* __restrict__ Wc4 = (const float4*)Wc;

    // ---------------- compress: zc = z @ Wc (+bc) ----------------
    // Each lane: 12 contiguous-by-wave z elements (3 float4), partials for all 8 d.
    // f32 FMA within a 4-element chunk, f64 chunk accumulation (decision path
    // needs ~1e-8 accuracy to avoid argmax tie flips vs the f64 np reference).
    double da0[8], da1[8];
#pragma unroll
    for (int d = 0; d < 8; ++d) { da0[d] = 0.0; da1[d] = 0.0; }

#pragma unroll
    for (int j = 0; j < 3; ++j) {
        const int fi = lane + 64 * j;                    // float4 index in row
        const float4 zv0 = z4[(size_t)row0 * 192 + fi];
        const float4 zv1 = z4[(size_t)row1 * 192 + fi];
        float f0[8], f1[8];
#pragma unroll
        for (int d = 0; d < 8; ++d) { f0[d] = 0.f; f1[d] = 0.f; }

#define COMP_STEP(comp, koff)                                              \
        {                                                                  \
            const int c = fi * 4 + (koff);                                 \
            const float4 wA = Wc4[c * 2];                                  \
            const float4 wB = Wc4[c * 2 + 1];                              \
            const float a0 = zv0.comp, a1 = zv1.comp;                      \
            f0[0] = fmaf(a0, wA.x, f0[0]); f0[1] = fmaf(a0, wA.y, f0[1]);  \
            f0[2] = fmaf(a0, wA.z, f0[2]); f0[3] = fmaf(a0, wA.w, f0[3]);  \
            f0[4] = fmaf(a0, wB.x, f0[4]); f0[5] = fmaf(a0, wB.y, f0[5]);  \
            f0[6] = fmaf(a0, wB.z, f0[6]); f0[7] = fmaf(a0, wB.w, f0[7]);  \
            f1[0] = fmaf(a1, wA.x, f1[0]); f1[1] = fmaf(a1, wA.y, f1[1]);  \
            f1[2] = fmaf(a1, wA.z, f1[2]); f1[3] = fmaf(a1, wA.w, f1[3]);  \
            f1[4] = fmaf(a1, wB.x, f1[4]); f1[5] = fmaf(a1, wB.y, f1[5]);  \
            f1[6] = fmaf(a1, wB.z, f1[6]); f1[7] = fmaf(a1, wB.w, f1[7]);  \
        }
        COMP_STEP(x, 0)
        COMP_STEP(y, 1)
        COMP_STEP(z, 2)
        COMP_STEP(w, 3)
#undef COMP_STEP

#pragma unroll
        for (int d = 0; d < 8; ++d) {
            da0[d] += (double)f0[d];
            da1[d] += (double)f1[d];
        }
    }

    // Distributing butterfly: reduce 8 per-lane partial arrays across 64 lanes,
    // delivering zc[d] to lanes with (lane&7)==d. f64, fixed order, no dynamic
    // register indexing (static selects only).
    const int b0 = lane & 1, b1 = (lane >> 1) & 1, b2 = (lane >> 2) & 1;
#define REDUCE_TO_MINE(da, out)                                            \
    {                                                                      \
        double k0 = b0 ? da[1] : da[0], s0 = b0 ? da[0] : da[1];           \
        double k1 = b0 ? da[3] : da[2], s1 = b0 ? da[2] : da[3];           \
        double k2 = b0 ? da[5] : da[4], s2 = b0 ? da[4] : da[5];           \
        double k3 = b0 ? da[7] : da[6], s3 = b0 ? da[6] : da[7];           \
        k0 += __shfl_xor(s0, 1); k1 += __shfl_xor(s1, 1);                  \
        k2 += __shfl_xor(s2, 1); k3 += __shfl_xor(s3, 1);                  \
        double m0 = b1 ? k1 : k0, t0 = b1 ? k0 : k1;                       \
        double m1 = b1 ? k3 : k2, t1 = b1 ? k2 : k3;                       \
        m0 += __shfl_xor(t0, 2); m1 += __shfl_xor(t1, 2);                  \
        double r = b2 ? m1 : m0, tq = b2 ? m0 : m1;                        \
        r += __shfl_xor(tq, 4);                                            \
        r += __shfl_xor(r, 8);                                             \
        r += __shfl_xor(r, 16);                                            \
        r += __shfl_xor(r, 32);                                            \
        out = r;                                                           \
    }
    double zc0, zc1;
    REDUCE_TO_MINE(da0, zc0)
    REDUCE_TO_MINE(da1, zc1)
#undef REDUCE_TO_MINE
    zc0 += bc_mine;
    zc1 += bc_mine;

    // ---------------- gumbel + argmax (per (row, dg)) ----------------
    // u[row][dg][lev] -> permuted-coalesced 256B read per row per wave
    const double uv0 = (double)u[(size_t)row0 * 64 + dg * 8 + lev] + 1e-10;
    const double uv1 = (double)u[(size_t)row1 * 64 + dg * 8 + lev] + 1e-10;
    const double g0 = -log(-log(uv0));
    const double g1 = -log(-log(uv1));
    double n0 = g0 - fabs(zc0 - (double)cb_mine);   // TAU = 1
    double n1 = g1 - fabs(zc1 - (double)cb_mine);

    int   l0 = lev, l1 = lev;
    float c0 = cb_mine, c1 = cb_mine;
#pragma unroll
    for (int s = 8; s <= 32; s <<= 1) {             // reduce over lev bits (3,4,5)
        const double on0 = __shfl_xor(n0, s);
        const int    ol0 = __shfl_xor(l0, s);
        const float  oc0 = __shfl_xor(c0, s);
        const bool   t0  = (on0 > n0) || (on0 == n0 && ol0 < l0);  // first-max tie-break
        n0 = t0 ? on0 : n0; l0 = t0 ? ol0 : l0; c0 = t0 ? oc0 : c0;
        const double on1 = __shfl_xor(n1, s);
        const int    ol1 = __shfl_xor(l1, s);
        const float  oc1 = __shfl_xor(c1, s);
        const bool   t1  = (on1 > n1) || (on1 == n1 && ol1 < l1);
        n1 = t1 ? on1 : n1; l1 = t1 ? ol1 : l1; c1 = t1 ? oc1 : c1;
    }
    // c0/c1: selected codebook value for dim dg (valid in every lane)

    // ---------------- quantization error partial ----------------
    // zc and c are constant across the 8 lev-replicas of each dg; xor 1/2/4
    // sums over dg within each replica group -> identical full-row sum in
    // every lane. One representative per wave contributes.
    const double e0 = zc0 - (double)c0;
    const double e1 = zc1 - (double)c1;
    double q = e0 * e0 + e1 * e1;
    q += __shfl_xor(q, 1);
    q += __shfl_xor(q, 2);
    q += __shfl_xor(q, 4);
    if (USE_BPART) {
        if (lane == 0) wsum[wid] = q;   // per-wave partial -> LDS (reduced after expand)
    } else {
        if (lane == 0) atomicAdd(bpart, q);   // legacy fallback (contended)
    }

    // broadcast all 8 codes to every lane
    float code0[8], code1[8];
#pragma unroll
    for (int d = 0; d < 8; ++d) {
        code0[d] = __shfl(c0, (lane & 56) | d);
        code1[d] = __shfl(c1, (lane & 56) | d);
    }

    // ---------------- expand: z_q = codes @ We + be ----------------
    const float4* __restrict__ We4 = (const float4*)We;
    const float4* __restrict__ be4 = (const float4*)be;
    float4* __restrict__ zq4 = (float4*)zq;
#pragma unroll
    for (int j = 0; j < 3; ++j) {
        const int fi = lane + 64 * j;
        const float4 bv = be4[fi];
        float4 o0 = bv, o1 = bv;
#pragma unroll
        for (int d = 0; d < 8; ++d) {
            const float4 wv = We4[d * 192 + fi];
            o0.x = fmaf(code0[d], wv.x, o0.x);
            o0.y = fmaf(code0[d], wv.y, o0.y);
            o0.z = fmaf(code0[d], wv.z, o0.z);
            o0.w = fmaf(code0[d], wv.w, o0.w);
            o1.x = fmaf(code1[d], wv.x, o1.x);
            o1.y = fmaf(code1[d], wv.y, o1.y);
            o1.z = fmaf(code1[d], wv.z, o1.z);
            o1.w = fmaf(code1[d], wv.w, o1.w);
        }
        zq4[(size_t)row0 * 192 + fi] = o0;
        zq4[(size_t)row1 * 192 + fi] = o1;
    }

    if (USE_BPART) {
        // block partial: fixed-order sum of the 4 wave partials -> one plain
        // store per block. Deterministic; zero atomic contention.
        __syncthreads();
        if (threadIdx.x == 0)
            bpart[blockIdx.x] = (wsum[0] + wsum[1]) + (wsum[2] + wsum[3]);
    }
}

// Deterministic fixed-order reduction of NBLOCKS partials -> mean -> out.
__global__ __launch_bounds__(256) void fsq_tail_bpart(
    const double* __restrict__ bpart, float* __restrict__ out)
{
    __shared__ double s[256];
    const int t = threadIdx.x;
    double a = 0.0;
    for (int i = 0; i < NBLOCKS / 256; ++i)       // 32 sequential, fixed order
        a += bpart[t * (NBLOCKS / 256) + i];
    s[t] = a;
    __syncthreads();
    for (int w = 128; w > 0; w >>= 1) {
        if (t < w) s[t] += s[t + w];
        __syncthreads();
    }
    if (t == 0) out[0] = (float)(s[0] * (1.0 / QCOUNT));
}

__global__ void fsq_tail_atomic(const double* __restrict__ qacc, float* __restrict__ out)
{
    out[0] = (float)(qacc[0] * (1.0 / QCOUNT));
}

extern "C" void kernel_launch(void* const* d_in, const int* in_sizes, int n_in,
                              void* d_out, int out_size, void* d_ws, size_t ws_size,
                              hipStream_t stream)
{
    const float* z  = (const float*)d_in[0];
    const float* u  = (const float*)d_in[1];
    const float* Wc = (const float*)d_in[2];
    const float* bc = (const float*)d_in[3];
    const float* We = (const float*)d_in[4];
    const float* be = (const float*)d_in[5];
    const float* cb = (const float*)d_in[6];
    // d_in[7] = codebook_mask: all levels == 8 -> mask all true, unused.

    float*  zq    = (float*)d_out;
    double* bpart = (double*)d_ws;

    if (ws_size >= (size_t)NBLOCKS * sizeof(double)) {
        // no memset needed: every block overwrites its own slot
        fsq_main<1><<<dim3(NBLOCKS), dim3(256), 0, stream>>>(z, u, Wc, bc, We, be, cb, zq, bpart);
        fsq_tail_bpart<<<dim3(1), dim3(256), 0, stream>>>(bpart, zq + (size_t)NROWS * CIN);
    } else {
        hipMemsetAsync(d_ws, 0, sizeof(double), stream);
        fsq_main<0><<<dim3(NBLOCKS), dim3(256), 0, stream>>>(z, u, Wc, bc, We, be, cb, zq, bpart);
        fsq_tail_atomic<<<dim3(1), dim3(1), 0, stream>>>(bpart, zq + (size_t)NROWS * CIN);
    }
}